// Round 1
// 478.731 us; speedup vs baseline: 1.0219x; 1.0219x over previous
//
#include <hip/hip_runtime.h>

typedef __attribute__((ext_vector_type(8))) short bf16x8;
typedef __attribute__((ext_vector_type(4))) float f32x4;

#define NROWS   65536
#define NSLICE  8
#define SLICESZ 4160
#define SETSZ   (NSLICE*SLICESZ)   // 33280 floats per iteration set
#define EPSV    1e-8f
#define RPITCH  264                 // rLT row pitch in halfwords (+8 pad)

// Fused streaming of the decoder loss into the kmeans launches:
//  - kmeans blocks:   blockIdx.x in [0, KB)
//  - streamer blocks: blockIdx.x in [KB, KB+SB), only on launches it=0..7
#define KB      256                 // kmeans blocks per launch (1/CU)
#define SB      256                 // streamer blocks per launch
#define SCHUNK  1048576             // float4 per array per streaming launch (8*SB*256*16 = 8388608 total)

// ---- ws layout (float offsets) ----
#define WS_DEC   0
#define WS_LOSS  1
#define WS_SETS  16                          // 9 sets (iters 0..8 write)
#define WS_X2    (WS_SETS + 9*SETSZ)         // 299536
#define WS_ENCB  (WS_X2 + NROWS)             // 365072
#define WS_EBF   (WS_ENCB + 2097152)
#define WS_END   (WS_EBF + 2097152)          // ~18.3 MB

static __device__ __forceinline__ unsigned short f2bf(float f) {
    union { float f; unsigned u; } v; v.f = f;
    unsigned u = v.u + 0x7fffu + ((v.u >> 16) & 1u);
    return (unsigned short)(u >> 16);
}
static __device__ __forceinline__ float bf2f(unsigned short h) {
    union { unsigned u; float f; } v; v.u = ((unsigned)h) << 16; return v.f;
}
static __device__ __forceinline__ uint4 pack8(const unsigned short* h) {
    uint4 o;
    o.x = h[0] | ((unsigned)h[1] << 16);
    o.y = h[2] | ((unsigned)h[3] << 16);
    o.z = h[4] | ((unsigned)h[5] << 16);
    o.w = h[6] | ((unsigned)h[7] << 16);
    return o;
}

// ---------------------------------------------------------------------------
// prep0: enc f32 -> encB (bf16 row-major), encBfrag (phase-2 B fragment
// order), x2[row] = |bf16(enc_row)|^2.  Grid 1024 x 256, 64 rows/block.
// ---------------------------------------------------------------------------
__global__ __launch_bounds__(256) void prep0(
    const float* __restrict__ enc, unsigned* __restrict__ encB,
    uint4* __restrict__ encBfrag, float* __restrict__ x2)
{
    __shared__ unsigned short L[64 * 64];
    int t = threadIdx.x;
    int rl = t >> 2, part = t & 3;
    int row = blockIdx.x * 64 + rl;
    const float4* src = (const float4*)(enc + (size_t)row * 64 + part * 16);
    unsigned short hv[16];
    float ss = 0.f;
    #pragma unroll
    for (int i = 0; i < 4; ++i) {
        float4 v = src[i];
        unsigned short a = f2bf(v.x), b = f2bf(v.y), c = f2bf(v.z), d = f2bf(v.w);
        hv[i*4+0] = a; hv[i*4+1] = b; hv[i*4+2] = c; hv[i*4+3] = d;
        float fa = bf2f(a), fb = bf2f(b), fc = bf2f(c), fd = bf2f(d);
        ss = fmaf(fa, fa, fmaf(fb, fb, fmaf(fc, fc, fmaf(fd, fd, ss))));
    }
    unsigned* dst = encB + ((size_t)row * 64 + part * 16) / 2;
    #pragma unroll
    for (int i = 0; i < 8; ++i) dst[i] = (unsigned)hv[2*i] | ((unsigned)hv[2*i+1] << 16);
    #pragma unroll
    for (int i = 0; i < 16; ++i) L[rl * 64 + part * 16 + i] = hv[i];
    ss += __shfl_xor(ss, 1, 64);
    ss += __shfl_xor(ss, 2, 64);
    if (part == 0) x2[row] = ss;
    __syncthreads();
    for (int e = t; e < 512; e += 256) {
        int rbl = e >> 8, dt = (e >> 6) & 3, lane = e & 63;
        int q = lane >> 4, c = lane & 15;
        unsigned short hw[8];
        #pragma unroll
        for (int j = 0; j < 8; ++j)
            hw[j] = L[(rbl * 32 + q * 8 + j) * 64 + dt * 16 + c];
        encBfrag[(size_t)blockIdx.x * 512 + e] = pack8(hw);
    }
}

// ---------------------------------------------------------------------------
// Fused k-means iteration, wave-owned-output-tile structure, PLUS fused
// decoder-loss streaming blocks (blockIdx.x >= KB) that use the otherwise
// idle memory pipe while the latency-bound kmeans blocks (1/CU, 4 waves)
// run.  Streamers use nontemporal loads so encB/encBfrag stay L2/L3
// resident across iterations.
// ---------------------------------------------------------------------------
__global__ __launch_bounds__(256, 3) void kmeans_main(
    const bf16x8* __restrict__ encB8, const bf16x8* __restrict__ encBfrag8,
    const float* __restrict__ enc, const float* __restrict__ prev_set,
    float* __restrict__ cur_set, const float* __restrict__ x2,
    float* __restrict__ loss_sum, int mode,
    const f32x4* __restrict__ Xs, const f32x4* __restrict__ Ds,
    float* __restrict__ dec_sum, int itchunk)
{
    // ---- streamer path: decoder-loss partial sum, no LDS, no barriers ----
    if (blockIdx.x >= KB) {
        const int tid = (blockIdx.x - KB) * 256 + threadIdx.x;   // 0..65535
        const size_t base = (size_t)itchunk * SCHUNK + tid;
        float s0 = 0.f, s1 = 0.f, s2 = 0.f, s3 = 0.f;
        #pragma unroll
        for (int h = 0; h < 2; ++h) {
            f32x4 xv[8], dv[8];
            #pragma unroll
            for (int u = 0; u < 8; ++u)
                xv[u] = __builtin_nontemporal_load(&Xs[base + (size_t)(h * 8 + u) * 65536]);
            #pragma unroll
            for (int u = 0; u < 8; ++u)
                dv[u] = __builtin_nontemporal_load(&Ds[base + (size_t)(h * 8 + u) * 65536]);
            #pragma unroll
            for (int u = 0; u < 8; ++u) {
                f32x4 d = xv[u] - dv[u];
                s0 = fmaf(d.x, d.x, s0);
                s1 = fmaf(d.y, d.y, s1);
                s2 = fmaf(d.z, d.z, s2);
                s3 = fmaf(d.w, d.w, s3);
            }
        }
        float s = (s0 + s1) + (s2 + s3);
        #pragma unroll
        for (int off = 32; off; off >>= 1) s += __shfl_down(s, off, 64);
        if ((threadIdx.x & 63) == 0) atomicAdd(dec_sum, s);
        return;
    }

    __shared__ union {
        unsigned short CsBf[4096];        // prologue: bf16 C[k][d]
        unsigned short rLT[64 * RPITCH];  // phase 1/2: r^T  [k][row_local]
    } U;
    __shared__ float x2L[256];
    __shared__ float c2L[64];
    __shared__ float rslL[64];
    __shared__ float rsumL[64];
    __shared__ float lredL[4];

    const int t = threadIdx.x;
    const int wave = t >> 6, lane = t & 63, q = lane >> 4, c = lane & 15;
    const int blockR0 = blockIdx.x * 256;

    // ---- prologue ----
    x2L[t] = x2[blockR0 + t];
    if (t < 64) {
        rsumL[t] = 0.f;
        float v = 0.f;
        if (mode != 0) {
            #pragma unroll
            for (int sl = 0; sl < NSLICE; ++sl)
                v += prev_set[sl * SLICESZ + 4096 + t];
        }
        rslL[t] = 1.f / (v + EPSV);
    }
    __syncthreads();

    float c2part[4];
    #pragma unroll
    for (int j = 0; j < 4; ++j) {
        int v4 = t + j * 256;      // f32x4 index into C (1024 total)
        int row = v4 >> 4;
        float vx, vy, vz, vw;
        if (mode == 0) {
            f32x4 e = ((const f32x4*)enc)[v4];
            vx = e.x; vy = e.y; vz = e.z; vw = e.w;
        } else {
            float sx = 0.f, sy = 0.f, sz = 0.f, sw = 0.f;
            #pragma unroll
            for (int sl = 0; sl < NSLICE; ++sl) {
                f32x4 u = ((const f32x4*)(prev_set + (size_t)sl * SLICESZ))[v4];
                sx += u.x; sy += u.y; sz += u.z; sw += u.w;
            }
            float inv = rslL[row];
            vx = sx * inv; vy = sy * inv; vz = sz * inv; vw = sw * inv;
        }
        ushort4 h;
        h.x = f2bf(vx); h.y = f2bf(vy); h.z = f2bf(vz); h.w = f2bf(vw);
        ((ushort4*)U.CsBf)[v4] = h;
        float fx = bf2f(h.x), fy = bf2f(h.y), fz = bf2f(h.z), fw = bf2f(h.w);
        c2part[j] = fmaf(fx, fx, fmaf(fy, fy, fmaf(fz, fz, fw * fw)));
    }
    #pragma unroll
    for (int j = 0; j < 4; ++j) {
        float p = c2part[j];
        p += __shfl_xor(p, 1, 64); p += __shfl_xor(p, 2, 64);
        p += __shfl_xor(p, 4, 64); p += __shfl_xor(p, 8, 64);
        if ((lane & 15) == 0) c2L[j * 16 + (t >> 4)] = p;
    }
    __syncthreads();

    bf16x8 bfr[2][4];
    #pragma unroll
    for (int kk2 = 0; kk2 < 2; ++kk2)
        #pragma unroll
        for (int nt = 0; nt < 4; ++nt)
            bfr[kk2][nt] = *(const bf16x8*)&U.CsBf[(nt * 16 + c) * 64 + kk2 * 32 + q * 8];
    float c2f[4];
    #pragma unroll
    for (int nt = 0; nt < 4; ++nt) c2f[nt] = c2L[nt * 16 + c];
    __syncthreads();   // CsBf dead; U.rLT may now be written

    // ---- phase 1 (+softmax), 2 passes of 128 rows ----
    const f32x4 z4 = {0.f, 0.f, 0.f, 0.f};
    float rs[4] = {0.f, 0.f, 0.f, 0.f};
    float lossacc = 0.f;
    #pragma unroll
    for (int p = 0; p < 2; ++p) {
        bf16x8 a2f[4];
        #pragma unroll
        for (int sub = 0; sub < 2; ++sub) {
            int arow = blockR0 + p * 128 + wave * 32 + 8 * (c >> 2) + sub * 4 + (c & 3);
            const bf16x8* ap = encB8 + (size_t)arow * 8 + q;
            bf16x8 a0 = ap[0], a1 = ap[4];
            f32x4 accf[4];
            #pragma unroll
            for (int nt = 0; nt < 4; ++nt) {
                f32x4 s = __builtin_amdgcn_mfma_f32_16x16x32_bf16(a0, bfr[0][nt], z4, 0, 0, 0);
                accf[nt]  = __builtin_amdgcn_mfma_f32_16x16x32_bf16(a1, bfr[1][nt], s,  0, 0, 0);
            }
            #pragma unroll
            for (int reg = 0; reg < 4; ++reg) {
                int rloc = p * 128 + wave * 32 + 8 * q + sub * 4 + reg;
                float x2r = x2L[rloc];
                float d2[4], mn = 3.4e38f;
                #pragma unroll
                for (int nt = 0; nt < 4; ++nt) {
                    float v = fmaxf(x2r + c2f[nt] - 2.f * accf[nt][reg], 0.f);
                    d2[nt] = v; mn = fminf(mn, v);
                }
                mn = fminf(mn, __shfl_xor(mn, 1, 64));
                mn = fminf(mn, __shfl_xor(mn, 2, 64));
                mn = fminf(mn, __shfl_xor(mn, 4, 64));
                mn = fminf(mn, __shfl_xor(mn, 8, 64));
                float e[4], s = 0.f, swd = 0.f;
                #pragma unroll
                for (int nt = 0; nt < 4; ++nt) {
                    float ev = __expf(mn - d2[nt]);
                    e[nt] = ev; s += ev; swd = fmaf(ev, d2[nt], swd);
                }
                s   += __shfl_xor(s, 1, 64);   swd += __shfl_xor(swd, 1, 64);
                s   += __shfl_xor(s, 2, 64);   swd += __shfl_xor(swd, 2, 64);
                s   += __shfl_xor(s, 4, 64);   swd += __shfl_xor(swd, 4, 64);
                s   += __shfl_xor(s, 8, 64);   swd += __shfl_xor(swd, 8, 64);
                float inv = 1.f / s;
                if (mode == 2 && c == 0) lossacc += swd * inv;
                #pragma unroll
                for (int nt = 0; nt < 4; ++nt) {
                    float rv = e[nt] * inv;
                    rs[nt] += rv;
                    a2f[nt][sub * 4 + reg] = (short)f2bf(rv);
                }
            }
        }
        if (mode != 2) {
            #pragma unroll
            for (int nt = 0; nt < 4; ++nt)
                *(bf16x8*)&U.rLT[(nt * 16 + c) * RPITCH + p * 128 + wave * 32 + 8 * q] = a2f[nt];
        }
    }

    if (mode != 2) {
        #pragma unroll
        for (int nt = 0; nt < 4; ++nt) {
            float v = rs[nt];
            v += __shfl_xor(v, 16, 64);
            v += __shfl_xor(v, 32, 64);
            if (q == 0) atomicAdd(&rsumL[nt * 16 + c], v);
        }
        __syncthreads();   // rLT visible, rsumL complete

        // ---- phase 2: wave owns k-rows mt=wave, all 8 row-subtiles ----
        const int mt = wave;
        f32x4 cacc[4];
        #pragma unroll
        for (int dt = 0; dt < 4; ++dt) cacc[dt] = z4;
        #pragma unroll
        for (int kk = 0; kk < 8; ++kk) {
            bf16x8 aA = *(const bf16x8*)&U.rLT[(mt * 16 + c) * RPITCH + kk * 32 + q * 8];
            #pragma unroll
            for (int dt = 0; dt < 4; ++dt) {
                bf16x8 bB = encBfrag8[((size_t)(blockIdx.x * 8 + kk) * 4 + dt) * 64 + lane];
                cacc[dt] = __builtin_amdgcn_mfma_f32_16x16x32_bf16(aA, bB, cacc[dt], 0, 0, 0);
            }
        }
        float* slice = cur_set + (size_t)(blockIdx.x & (NSLICE - 1)) * SLICESZ;
        #pragma unroll
        for (int dt = 0; dt < 4; ++dt)
            #pragma unroll
            for (int reg = 0; reg < 4; ++reg)
                atomicAdd(&slice[(mt * 16 + q * 4 + reg) * 64 + dt * 16 + c],
                          cacc[dt][reg]);
        if (t < 64) atomicAdd(&slice[4096 + t], rsumL[t]);
    } else {
        #pragma unroll
        for (int off = 32; off; off >>= 1) lossacc += __shfl_down(lossacc, off, 64);
        if (lane == 0) lredL[wave] = lossacc;
        __syncthreads();
        if (t == 0) atomicAdd(loss_sum, lredL[0] + lredL[1] + lredL[2] + lredL[3]);
    }
}

// ---------------------------------------------------------------------------
__global__ void finalize_kernel(const float* __restrict__ dec_sum,
                                const float* __restrict__ loss_sum,
                                float* __restrict__ out)
{
    out[0] = dec_sum[0] * (1.f / (65536.f * 512.f))
           + 0.001f * (loss_sum[0] * (1.f / 65536.f));
}

// ---------------------------------------------------------------------------
extern "C" void kernel_launch(void* const* d_in, const int* in_sizes, int n_in,
                              void* d_out, int out_size, void* d_ws, size_t ws_size,
                              hipStream_t stream)
{
    const float* X   = (const float*)d_in[0];
    const float* enc = (const float*)d_in[1];
    const float* dec = (const float*)d_in[2];

    float* ws = (float*)d_ws;
    float* dec_sum  = ws + WS_DEC;
    float* loss_sum = ws + WS_LOSS;
    float* sets = ws + WS_SETS;
    float* x2   = ws + WS_X2;
    unsigned* encB  = (unsigned*)(ws + WS_ENCB);
    uint4* encBfrag = (uint4*)(ws + WS_EBF);

    hipMemsetAsync(d_ws, 0, (size_t)WS_X2 * sizeof(float), stream);

    prep0<<<dim3(1024), dim3(256), 0, stream>>>(enc, encB, encBfrag, x2);

    const bf16x8* encB8 = (const bf16x8*)encB;
    const bf16x8* eBf8  = (const bf16x8*)encBfrag;

    for (int it = 0; it < 10; ++it) {
        int mode = (it == 0) ? 0 : ((it == 9) ? 2 : 1);
        const float* prev = (it == 0) ? sets : sets + (size_t)(it - 1) * SETSZ;
        float* cur = (it < 9) ? sets + (size_t)it * SETSZ : sets;
        int grid = (it < 8) ? (KB + SB) : KB;
        kmeans_main<<<dim3(grid), dim3(256), 0, stream>>>(
            encB8, eBf8, enc, prev, cur, x2, loss_sum, mode,
            (const f32x4*)X, (const f32x4*)dec, dec_sum, it);
    }
    finalize_kernel<<<1, 1, 0, stream>>>(dec_sum, loss_sum, (float*)d_out);
}

// Round 2
// 474.963 us; speedup vs baseline: 1.0300x; 1.0079x over previous
//
#include <hip/hip_runtime.h>

typedef __attribute__((ext_vector_type(8))) short bf16x8;
typedef __attribute__((ext_vector_type(4))) float f32x4;

#define NROWS   65536
#define NSLICE  8
#define SLICESZ 4160
#define SETSZ   (NSLICE*SLICESZ)   // 33280 floats per iteration set
#define EPSV    1e-8f
#define RPITCH  264                 // rLT row pitch in halfwords (+8 pad)

// Fused streaming of the decoder loss into the kmeans launches:
//  - kmeans blocks:   blockIdx.x in [0, KB)
//  - streamer blocks: blockIdx.x in [KB, KB+SB), only on launches it=0..7
#define KB      256                 // kmeans blocks per launch (1/CU)
#define SB      256                 // streamer blocks per launch
#define SCHUNK  1048576             // float4 per array per streaming launch

// ---- ws layout (float offsets) ----
#define WS_DEC   0
#define WS_LOSS  1
#define WS_SETS  16                          // 9 sets (iters 0..8 write)
#define WS_X2    (WS_SETS + 9*SETSZ)         // 299536
#define WS_ENCB  (WS_X2 + NROWS)             // 365072
#define WS_EBF   (WS_ENCB + 2097152)
#define WS_END   (WS_EBF + 2097152)          // ~18.3 MB

static __device__ __forceinline__ unsigned short f2bf(float f) {
    union { float f; unsigned u; } v; v.f = f;
    unsigned u = v.u + 0x7fffu + ((v.u >> 16) & 1u);
    return (unsigned short)(u >> 16);
}
static __device__ __forceinline__ float bf2f(unsigned short h) {
    union { unsigned u; float f; } v; v.u = ((unsigned)h) << 16; return v.f;
}
static __device__ __forceinline__ uint4 pack8(const unsigned short* h) {
    uint4 o;
    o.x = h[0] | ((unsigned)h[1] << 16);
    o.y = h[2] | ((unsigned)h[3] << 16);
    o.z = h[4] | ((unsigned)h[5] << 16);
    o.w = h[6] | ((unsigned)h[7] << 16);
    return o;
}

// ---------------------------------------------------------------------------
// prep0: enc f32 -> encB (bf16 row-major), encBfrag (phase-2 B fragment
// order), x2[row] = |bf16(enc_row)|^2.  Grid 1024 x 256, 64 rows/block.
// ---------------------------------------------------------------------------
__global__ __launch_bounds__(256) void prep0(
    const float* __restrict__ enc, unsigned* __restrict__ encB,
    uint4* __restrict__ encBfrag, float* __restrict__ x2)
{
    __shared__ unsigned short L[64 * 64];
    int t = threadIdx.x;
    int rl = t >> 2, part = t & 3;
    int row = blockIdx.x * 64 + rl;
    const float4* src = (const float4*)(enc + (size_t)row * 64 + part * 16);
    unsigned short hv[16];
    float ss = 0.f;
    #pragma unroll
    for (int i = 0; i < 4; ++i) {
        float4 v = src[i];
        unsigned short a = f2bf(v.x), b = f2bf(v.y), c = f2bf(v.z), d = f2bf(v.w);
        hv[i*4+0] = a; hv[i*4+1] = b; hv[i*4+2] = c; hv[i*4+3] = d;
        float fa = bf2f(a), fb = bf2f(b), fc = bf2f(c), fd = bf2f(d);
        ss = fmaf(fa, fa, fmaf(fb, fb, fmaf(fc, fc, fmaf(fd, fd, ss))));
    }
    unsigned* dst = encB + ((size_t)row * 64 + part * 16) / 2;
    #pragma unroll
    for (int i = 0; i < 8; ++i) dst[i] = (unsigned)hv[2*i] | ((unsigned)hv[2*i+1] << 16);
    #pragma unroll
    for (int i = 0; i < 16; ++i) L[rl * 64 + part * 16 + i] = hv[i];
    ss += __shfl_xor(ss, 1, 64);
    ss += __shfl_xor(ss, 2, 64);
    if (part == 0) x2[row] = ss;
    __syncthreads();
    for (int e = t; e < 512; e += 256) {
        int rbl = e >> 8, dt = (e >> 6) & 3, lane = e & 63;
        int q = lane >> 4, c = lane & 15;
        unsigned short hw[8];
        #pragma unroll
        for (int j = 0; j < 8; ++j)
            hw[j] = L[(rbl * 32 + q * 8 + j) * 64 + dt * 16 + c];
        encBfrag[(size_t)blockIdx.x * 512 + e] = pack8(hw);
    }
}

// ---------------------------------------------------------------------------
// Fused k-means iteration, wave-owned-output-tile structure, PLUS fused
// decoder-loss streaming blocks (blockIdx.x >= KB).
// Streamer path: load-and-consume-immediately so the scheduler only keeps
// as many NT loads in flight as the VGPR budget allows (the previous
// array-batched form forced 128 live VGPRs -> scratch spills -> the
// streamer serialized behind the kmeans block instead of hiding under it).
// __launch_bounds__(256,2): resident occupancy on fused launches is only
// 2 blocks/CU (2 waves/SIMD), so a 128-VGPR budget costs nothing.
// ---------------------------------------------------------------------------
__global__ __launch_bounds__(256, 2) void kmeans_main(
    const bf16x8* __restrict__ encB8, const bf16x8* __restrict__ encBfrag8,
    const float* __restrict__ enc, const float* __restrict__ prev_set,
    float* __restrict__ cur_set, const float* __restrict__ x2,
    float* __restrict__ loss_sum, int mode,
    const f32x4* __restrict__ Xs, const f32x4* __restrict__ Ds,
    float* __restrict__ dec_sum, int itchunk)
{
    // ---- streamer path: decoder-loss partial sum, no LDS, no barriers ----
    if (blockIdx.x >= KB) {
        const int tid = (blockIdx.x - KB) * 256 + threadIdx.x;   // 0..65535
        const size_t base = (size_t)itchunk * SCHUNK + tid;
        float s0 = 0.f, s1 = 0.f, s2 = 0.f, s3 = 0.f;
        #pragma unroll
        for (int h = 0; h < 8; ++h) {
            f32x4 x0 = __builtin_nontemporal_load(&Xs[base + (size_t)(2 * h    ) * 65536]);
            f32x4 d0 = __builtin_nontemporal_load(&Ds[base + (size_t)(2 * h    ) * 65536]);
            f32x4 x1 = __builtin_nontemporal_load(&Xs[base + (size_t)(2 * h + 1) * 65536]);
            f32x4 d1 = __builtin_nontemporal_load(&Ds[base + (size_t)(2 * h + 1) * 65536]);
            f32x4 a = x0 - d0;
            f32x4 b = x1 - d1;
            s0 = fmaf(a.x, a.x, s0); s1 = fmaf(a.y, a.y, s1);
            s2 = fmaf(a.z, a.z, s2); s3 = fmaf(a.w, a.w, s3);
            s0 = fmaf(b.x, b.x, s0); s1 = fmaf(b.y, b.y, s1);
            s2 = fmaf(b.z, b.z, s2); s3 = fmaf(b.w, b.w, s3);
        }
        float s = (s0 + s1) + (s2 + s3);
        #pragma unroll
        for (int off = 32; off; off >>= 1) s += __shfl_down(s, off, 64);
        if ((threadIdx.x & 63) == 0) atomicAdd(dec_sum, s);
        return;
    }

    __shared__ union {
        unsigned short CsBf[4096];        // prologue: bf16 C[k][d]
        unsigned short rLT[64 * RPITCH];  // phase 1/2: r^T  [k][row_local]
    } U;
    __shared__ float x2L[256];
    __shared__ float c2L[64];
    __shared__ float rslL[64];
    __shared__ float rsumL[64];
    __shared__ float lredL[4];

    const int t = threadIdx.x;
    const int wave = t >> 6, lane = t & 63, q = lane >> 4, c = lane & 15;
    const int blockR0 = blockIdx.x * 256;

    // ---- prologue ----
    x2L[t] = x2[blockR0 + t];
    if (t < 64) {
        rsumL[t] = 0.f;
        float v = 0.f;
        if (mode != 0) {
            #pragma unroll
            for (int sl = 0; sl < NSLICE; ++sl)
                v += prev_set[sl * SLICESZ + 4096 + t];
        }
        rslL[t] = 1.f / (v + EPSV);
    }
    __syncthreads();

    float c2part[4];
    #pragma unroll
    for (int j = 0; j < 4; ++j) {
        int v4 = t + j * 256;      // f32x4 index into C (1024 total)
        int row = v4 >> 4;
        float vx, vy, vz, vw;
        if (mode == 0) {
            f32x4 e = ((const f32x4*)enc)[v4];
            vx = e.x; vy = e.y; vz = e.z; vw = e.w;
        } else {
            float sx = 0.f, sy = 0.f, sz = 0.f, sw = 0.f;
            #pragma unroll
            for (int sl = 0; sl < NSLICE; ++sl) {
                f32x4 u = ((const f32x4*)(prev_set + (size_t)sl * SLICESZ))[v4];
                sx += u.x; sy += u.y; sz += u.z; sw += u.w;
            }
            float inv = rslL[row];
            vx = sx * inv; vy = sy * inv; vz = sz * inv; vw = sw * inv;
        }
        ushort4 h;
        h.x = f2bf(vx); h.y = f2bf(vy); h.z = f2bf(vz); h.w = f2bf(vw);
        ((ushort4*)U.CsBf)[v4] = h;
        float fx = bf2f(h.x), fy = bf2f(h.y), fz = bf2f(h.z), fw = bf2f(h.w);
        c2part[j] = fmaf(fx, fx, fmaf(fy, fy, fmaf(fz, fz, fw * fw)));
    }
    #pragma unroll
    for (int j = 0; j < 4; ++j) {
        float p = c2part[j];
        p += __shfl_xor(p, 1, 64); p += __shfl_xor(p, 2, 64);
        p += __shfl_xor(p, 4, 64); p += __shfl_xor(p, 8, 64);
        if ((lane & 15) == 0) c2L[j * 16 + (t >> 4)] = p;
    }
    __syncthreads();

    bf16x8 bfr[2][4];
    #pragma unroll
    for (int kk2 = 0; kk2 < 2; ++kk2)
        #pragma unroll
        for (int nt = 0; nt < 4; ++nt)
            bfr[kk2][nt] = *(const bf16x8*)&U.CsBf[(nt * 16 + c) * 64 + kk2 * 32 + q * 8];
    float c2f[4];
    #pragma unroll
    for (int nt = 0; nt < 4; ++nt) c2f[nt] = c2L[nt * 16 + c];
    __syncthreads();   // CsBf dead; U.rLT may now be written

    // ---- phase 1 (+softmax), 2 passes of 128 rows ----
    const f32x4 z4 = {0.f, 0.f, 0.f, 0.f};
    float rs[4] = {0.f, 0.f, 0.f, 0.f};
    float lossacc = 0.f;
    #pragma unroll
    for (int p = 0; p < 2; ++p) {
        bf16x8 a2f[4];
        #pragma unroll
        for (int sub = 0; sub < 2; ++sub) {
            int arow = blockR0 + p * 128 + wave * 32 + 8 * (c >> 2) + sub * 4 + (c & 3);
            const bf16x8* ap = encB8 + (size_t)arow * 8 + q;
            bf16x8 a0 = ap[0], a1 = ap[4];
            f32x4 accf[4];
            #pragma unroll
            for (int nt = 0; nt < 4; ++nt) {
                f32x4 s = __builtin_amdgcn_mfma_f32_16x16x32_bf16(a0, bfr[0][nt], z4, 0, 0, 0);
                accf[nt]  = __builtin_amdgcn_mfma_f32_16x16x32_bf16(a1, bfr[1][nt], s,  0, 0, 0);
            }
            #pragma unroll
            for (int reg = 0; reg < 4; ++reg) {
                int rloc = p * 128 + wave * 32 + 8 * q + sub * 4 + reg;
                float x2r = x2L[rloc];
                float d2[4], mn = 3.4e38f;
                #pragma unroll
                for (int nt = 0; nt < 4; ++nt) {
                    float v = fmaxf(x2r + c2f[nt] - 2.f * accf[nt][reg], 0.f);
                    d2[nt] = v; mn = fminf(mn, v);
                }
                mn = fminf(mn, __shfl_xor(mn, 1, 64));
                mn = fminf(mn, __shfl_xor(mn, 2, 64));
                mn = fminf(mn, __shfl_xor(mn, 4, 64));
                mn = fminf(mn, __shfl_xor(mn, 8, 64));
                float e[4], s = 0.f, swd = 0.f;
                #pragma unroll
                for (int nt = 0; nt < 4; ++nt) {
                    float ev = __expf(mn - d2[nt]);
                    e[nt] = ev; s += ev; swd = fmaf(ev, d2[nt], swd);
                }
                s   += __shfl_xor(s, 1, 64);   swd += __shfl_xor(swd, 1, 64);
                s   += __shfl_xor(s, 2, 64);   swd += __shfl_xor(swd, 2, 64);
                s   += __shfl_xor(s, 4, 64);   swd += __shfl_xor(swd, 4, 64);
                s   += __shfl_xor(s, 8, 64);   swd += __shfl_xor(swd, 8, 64);
                float inv = 1.f / s;
                if (mode == 2 && c == 0) lossacc += swd * inv;
                #pragma unroll
                for (int nt = 0; nt < 4; ++nt) {
                    float rv = e[nt] * inv;
                    rs[nt] += rv;
                    a2f[nt][sub * 4 + reg] = (short)f2bf(rv);
                }
            }
        }
        if (mode != 2) {
            #pragma unroll
            for (int nt = 0; nt < 4; ++nt)
                *(bf16x8*)&U.rLT[(nt * 16 + c) * RPITCH + p * 128 + wave * 32 + 8 * q] = a2f[nt];
        }
    }

    if (mode != 2) {
        #pragma unroll
        for (int nt = 0; nt < 4; ++nt) {
            float v = rs[nt];
            v += __shfl_xor(v, 16, 64);
            v += __shfl_xor(v, 32, 64);
            if (q == 0) atomicAdd(&rsumL[nt * 16 + c], v);
        }
        __syncthreads();   // rLT visible, rsumL complete

        // ---- phase 2: wave owns k-rows mt=wave, all 8 row-subtiles ----
        const int mt = wave;
        f32x4 cacc[4];
        #pragma unroll
        for (int dt = 0; dt < 4; ++dt) cacc[dt] = z4;
        #pragma unroll
        for (int kk = 0; kk < 8; ++kk) {
            bf16x8 aA = *(const bf16x8*)&U.rLT[(mt * 16 + c) * RPITCH + kk * 32 + q * 8];
            #pragma unroll
            for (int dt = 0; dt < 4; ++dt) {
                bf16x8 bB = encBfrag8[((size_t)(blockIdx.x * 8 + kk) * 4 + dt) * 64 + lane];
                cacc[dt] = __builtin_amdgcn_mfma_f32_16x16x32_bf16(aA, bB, cacc[dt], 0, 0, 0);
            }
        }
        float* slice = cur_set + (size_t)(blockIdx.x & (NSLICE - 1)) * SLICESZ;
        #pragma unroll
        for (int dt = 0; dt < 4; ++dt)
            #pragma unroll
            for (int reg = 0; reg < 4; ++reg)
                atomicAdd(&slice[(mt * 16 + q * 4 + reg) * 64 + dt * 16 + c],
                          cacc[dt][reg]);
        if (t < 64) atomicAdd(&slice[4096 + t], rsumL[t]);
    } else {
        #pragma unroll
        for (int off = 32; off; off >>= 1) lossacc += __shfl_down(lossacc, off, 64);
        if (lane == 0) lredL[wave] = lossacc;
        __syncthreads();
        if (t == 0) atomicAdd(loss_sum, lredL[0] + lredL[1] + lredL[2] + lredL[3]);
    }
}

// ---------------------------------------------------------------------------
__global__ void finalize_kernel(const float* __restrict__ dec_sum,
                                const float* __restrict__ loss_sum,
                                float* __restrict__ out)
{
    out[0] = dec_sum[0] * (1.f / (65536.f * 512.f))
           + 0.001f * (loss_sum[0] * (1.f / 65536.f));
}

// ---------------------------------------------------------------------------
extern "C" void kernel_launch(void* const* d_in, const int* in_sizes, int n_in,
                              void* d_out, int out_size, void* d_ws, size_t ws_size,
                              hipStream_t stream)
{
    const float* X   = (const float*)d_in[0];
    const float* enc = (const float*)d_in[1];
    const float* dec = (const float*)d_in[2];

    float* ws = (float*)d_ws;
    float* dec_sum  = ws + WS_DEC;
    float* loss_sum = ws + WS_LOSS;
    float* sets = ws + WS_SETS;
    float* x2   = ws + WS_X2;
    unsigned* encB  = (unsigned*)(ws + WS_ENCB);
    uint4* encBfrag = (uint4*)(ws + WS_EBF);

    hipMemsetAsync(d_ws, 0, (size_t)WS_X2 * sizeof(float), stream);

    prep0<<<dim3(1024), dim3(256), 0, stream>>>(enc, encB, encBfrag, x2);

    const bf16x8* encB8 = (const bf16x8*)encB;
    const bf16x8* eBf8  = (const bf16x8*)encBfrag;

    for (int it = 0; it < 10; ++it) {
        int mode = (it == 0) ? 0 : ((it == 9) ? 2 : 1);
        const float* prev = (it == 0) ? sets : sets + (size_t)(it - 1) * SETSZ;
        float* cur = (it < 9) ? sets + (size_t)it * SETSZ : sets;
        int grid = (it < 8) ? (KB + SB) : KB;
        kmeans_main<<<dim3(grid), dim3(256), 0, stream>>>(
            encB8, eBf8, enc, prev, cur, x2, loss_sum, mode,
            (const f32x4*)X, (const f32x4*)dec, dec_sum, it);
    }
    finalize_kernel<<<1, 1, 0, stream>>>(dec_sum, loss_sum, (float*)d_out);
}